// Round 5
// baseline (219.744 us; speedup 1.0000x reference)
//
#include <hip/hip_runtime.h>

// YOLOv1 loss: 802816 rows x 30 f32, two tensors, scalar out.
// R5: R2-R4 showed the compiler will never batch VGPR loads (it minimizes
// registers: VGPR=24/36/32, ~1KB/CU in flight, 2.6 TB/s latency-bound).
// Fix: async global->LDS DMA (global_load_lds width=16), double-buffered,
// ONE WAVE per block => no barriers; s_waitcnt vmcnt(30) keeps the next
// tile's 30KB in flight during compute. 2 blocks/CU => 60KB/CU in flight.

#define COLS 30
#define TROWS 128                 // rows per tile
#define TBYTES (TROWS * COLS * 4) // 15360 B per tensor per tile
#define NT2 6272                  // 802816 / 128 tiles
#define GRID1 512                 // 2 blocks/CU
// blocks 0..127 process 13 tiles, 128..511 process 12 (6272 = 512*12 + 128)

// Per-row loss math from two float2 streams (LDS or global). Bit-exact.
__device__ __forceinline__ void row_compute_f2(
    const float2* __restrict__ P2, const float2* __restrict__ T2,
    bool& coord, float& r, float& noo)
{
    float2 a0 = P2[0],  a1 = P2[1],  a2 = P2[2],  a3 = P2[3],  a4 = P2[4];
    float2 a5 = P2[5],  a6 = P2[6],  a7 = P2[7],  a8 = P2[8],  a9 = P2[9];
    float2 a10 = P2[10], a11 = P2[11], a12 = P2[12], a13 = P2[13], a14 = P2[14];
    float2 b0 = T2[0],  b1 = T2[1],  b2 = T2[2],  b3 = T2[3],  b4 = T2[4];
    float2 b5 = T2[5],  b6 = T2[6],  b7 = T2[7],  b8 = T2[8],  b9 = T2[9];
    float2 b10 = T2[10], b11 = T2[11], b12 = T2[12], b13 = T2[13], b14 = T2[14];

    const float C = 1.0f / 7.0f;
    float conf = b2.x;                    // T[4], exactly 0.0 or 1.0
    coord = (conf == 1.0f);
    noo = 0.0f;
    if (conf == 0.0f) {
        float d4 = a2.x - conf;
        float d9 = a4.y - b4.y;
        noo = d4 * d4 + d9 * d9;
    }
    float T0 = b0.x, T1 = b0.y, T2v = b1.x, T3 = b1.y;
    float tb0 = T0 * T0, tb1 = T1 * T1, tb2 = T2v * T2v, tb3 = T3 * T3;
    float tax = tb0 * C - tb2, tay = tb1 * C - tb3;
    float tbx = tax * C + tb2, tby = tay * C + tb3;
    float areaT = (tbx - tax) * (tby - tay);
    float pax0 = a0.x * C - a1.x, pay0 = a0.y * C - a1.y;
    float pbx0 = pax0 * C + a1.x, pby0 = pay0 * C + a1.y;
    float pax1 = a2.y * C - a3.y, pay1 = a3.x * C - a4.x;
    float pbx1 = pax1 * C + a3.y, pby1 = pay1 * C + a4.x;
    float ltx = fmaxf(pax0, tax), lty = fmaxf(pay0, tay);
    float rbx = fminf(pbx0, tbx), rby = fminf(pby0, tby);
    float wx = fmaxf(rbx - ltx, 0.0f), wy = fmaxf(rby - lty, 0.0f);
    float inter = wx * wy;
    float areaP = (pbx0 - pax0) * (pby0 - pay0);
    float iou0 = inter / (areaP + areaT - inter);
    ltx = fmaxf(pax1, tax); lty = fmaxf(pay1, tay);
    rbx = fminf(pbx1, tbx); rby = fminf(pby1, tby);
    wx = fmaxf(rbx - ltx, 0.0f); wy = fmaxf(rby - lty, 0.0f);
    inter = wx * wy;
    areaP = (pbx1 - pax1) * (pby1 - pay1);
    float iou1 = inter / (areaP + areaT - inter);

    int idx = (iou1 > iou0) ? 1 : 0;
    float sx = idx ? a2.y : a0.x;
    float sy = idx ? a3.x : a0.y;
    float sw = idx ? a3.y : a1.x;
    float sh = idx ? a4.x : a1.y;
    float best = b5.x, pc = a5.x;
#define CLS_STEP(tv, pv) { float v_ = (tv); if (v_ > best) { best = v_; pc = (pv); } }
    CLS_STEP(b5.y,  a5.y)  CLS_STEP(b6.x,  a6.x)  CLS_STEP(b6.y,  a6.y)
    CLS_STEP(b7.x,  a7.x)  CLS_STEP(b7.y,  a7.y)  CLS_STEP(b8.x,  a8.x)
    CLS_STEP(b8.y,  a8.y)  CLS_STEP(b9.x,  a9.x)  CLS_STEP(b9.y,  a9.y)
    CLS_STEP(b10.x, a10.x) CLS_STEP(b10.y, a10.y) CLS_STEP(b11.x, a11.x)
    CLS_STEP(b11.y, a11.y) CLS_STEP(b12.x, a12.x) CLS_STEP(b12.y, a12.y)
    CLS_STEP(b13.x, a13.x) CLS_STEP(b13.y, a13.y) CLS_STEP(b14.x, a14.x)
    CLS_STEP(b14.y, a14.y)
#undef CLS_STEP
    float d0 = sx - T0, d1 = sy - T1, d2 = sw - T2v, d3 = sh - T3;
    float dc = pc - 1.0f;
    r = d0 * d0 + d1 * d1 + d2 * d2 + d3 * d3 + 2.0f * dc * dc;
}

// Async-DMA stage of one 128-row tile of both tensors into an LDS buffer.
// 64 lanes x 16 B x 15 rounds per tensor; LDS dest = uniform base + lane*16
// (the HW constraint), which matches the contiguous row-major layout.
__device__ __forceinline__ void stage_tile(const float* __restrict__ gp,
                                           const float* __restrict__ gt,
                                           float* lbuf, long tile, int tid) {
    const char* gpb = (const char*)gp + tile * (long)TBYTES;
    const char* gtb = (const char*)gt + tile * (long)TBYTES;
    char* lb = (char*)lbuf;
    asm volatile("" ::: "memory");
#pragma unroll
    for (int r = 0; r < 15; ++r) {
        int off = r * 1024 + tid * 16;
        __builtin_amdgcn_global_load_lds(
            (const __attribute__((address_space(1))) void*)(gpb + off),
            (__attribute__((address_space(3))) void*)(lb + off), 16, 0, 0);
    }
#pragma unroll
    for (int r = 0; r < 15; ++r) {
        int off = r * 1024 + tid * 16;
        __builtin_amdgcn_global_load_lds(
            (const __attribute__((address_space(1))) void*)(gtb + off),
            (__attribute__((address_space(3))) void*)(lb + TBYTES + off), 16, 0, 0);
    }
    asm volatile("" ::: "memory");
}

// K1: one wave per block, double-buffered LDS pipeline over 12-13 tiles.
// Per tile writes stats[tile] = {count, sum_coord_r, sum_noobj, 0}.
__global__ __launch_bounds__(64, 1) void yolo_k1(const float* __restrict__ gp,
                                                 const float* __restrict__ gt,
                                                 float4* __restrict__ stats) {
    __shared__ float buf[2][2 * TROWS * COLS];   // 2 x 30720 B
    int tid = threadIdx.x;                        // 0..63 (one wave)
    int bid = blockIdx.x;
    int ntiles = 12 + (bid < (NT2 - GRID1 * 12) ? 1 : 0);

    stage_tile(gp, gt, buf[0], bid, tid);
    for (int j = 0; j < ntiles; ++j) {
        long tile = (long)bid + (long)j * GRID1;
        int cur = j & 1;
        bool has_next = (j + 1 < ntiles);
        if (has_next)
            stage_tile(gp, gt, buf[cur ^ 1], (long)bid + (long)(j + 1) * GRID1, tid);
        // Drain ONLY the current tile's 30 DMAs (+ stray stat store); the
        // next tile's 30 stay in flight through compute. No barriers: this
        // wave is the only reader/writer of its LDS.
        if (has_next) asm volatile("s_waitcnt vmcnt(30)" ::: "memory");
        else          asm volatile("s_waitcnt vmcnt(0)"  ::: "memory");

        const float* lp = buf[cur];
        const float* lt = buf[cur] + TROWS * COLS;
        bool cA, cB; float rA, rB, nA, nB;
        row_compute_f2((const float2*)(lp + tid * COLS),
                       (const float2*)(lt + tid * COLS), cA, rA, nA);
        row_compute_f2((const float2*)(lp + (tid + 64) * COLS),
                       (const float2*)(lt + (tid + 64) * COLS), cB, rB, nB);
        float rl = (cA ? rA : 0.0f) + (cB ? rB : 0.0f);
        float nn = nA + nB;
        int c = (int)__popcll(__ballot(cA)) + (int)__popcll(__ballot(cB));
#pragma unroll
        for (int off = 32; off > 0; off >>= 1) {
            rl += __shfl_down(rl, off);
            nn += __shfl_down(nn, off);
        }
        if (tid == 0) stats[tile] = make_float4((float)c, rl, nn, 0.0f);
        asm volatile("" ::: "memory");
    }
}

// K2: totals + scan over 6272 tile-stats + boundary-tile (128 rows) fixup.
__global__ __launch_bounds__(256) void yolo_k2(const float4* __restrict__ stats,
                                               const float* __restrict__ gp,
                                               const float* __restrict__ gt,
                                               float* __restrict__ out) {
    __shared__ int   wsum[4];
    __shared__ float wf[4], wn2[4];
    __shared__ int   s_bstar, s_kstar;
    __shared__ float s_base;
    __shared__ int   s_wcnt[4];
    int tid = threadIdx.x;
    int lane = tid & 63, wave = tid >> 6;
    if (tid == 0) { s_bstar = -1; s_kstar = 0; }

    const int PER = 25;                 // 256*25 = 6400 >= 6272
    int start = tid * PER;
    int end = min(NT2, start + PER);

    int cloc = 0; float nloc = 0.0f;
    for (int i = start; i < end; ++i) {
        float4 s = stats[i];
        cloc += (int)s.x; nloc += s.z;
    }

    int incl = cloc;                    // inclusive shfl scan within wave
#pragma unroll
    for (int off = 1; off < 64; off <<= 1) {
        int v = __shfl_up(incl, off);
        if (lane >= off) incl += v;
    }
    if (lane == 63) wsum[wave] = incl;
    __syncthreads();                    // also orders s_bstar init vs walk
    int woff = 0;
#pragma unroll
    for (int w = 0; w < 4; ++w) woff += (w < wave) ? wsum[w] : 0;
    int ex = woff + incl - cloc;        // exclusive global prefix
    int n_obj = wsum[0] + wsum[1] + wsum[2] + wsum[3];
    int n_half = n_obj >> 1;

    float acc = 0.0f;
    int running = ex;
    for (int i = start; i < end; ++i) {
        float4 s = stats[i];
        int ci = (int)s.x;
        if (ci > 0) {
            if (running + ci <= n_half) {
                acc += s.y;
            } else if (running < n_half) {  // exactly one thread ever
                s_bstar = i;
                s_kstar = n_half - running;
            }
        }
        running += ci;
    }

#pragma unroll
    for (int off = 32; off > 0; off >>= 1) {
        acc  += __shfl_down(acc, off);
        nloc += __shfl_down(nloc, off);
    }
    if (lane == 0) { wf[wave] = acc; wn2[wave] = nloc; }
    __syncthreads();
    if (tid == 0)
        s_base = 5.0f * (wf[0] + wf[1] + wf[2] + wf[3])
               + 0.5f * (wn2[0] + wn2[1] + wn2[2] + wn2[3]);
    __syncthreads();

    // Phase B: boundary tile fixup (128 rows; threads >=128 sit out)
    int bstar = s_bstar, kstar = s_kstar;
    float total = 0.0f;
    if (bstar >= 0) {                    // uniform branch
        bool coord = false; float r = 0.0f;
        if (tid < TROWS) {
            long row = (long)bstar * TROWS + tid;
            float nthrow;
            row_compute_f2((const float2*)(gp + row * (long)COLS),
                           (const float2*)(gt + row * (long)COLS),
                           coord, r, nthrow);
        }
        unsigned long long bal = __ballot(coord);
        if (lane == 0) s_wcnt[wave] = (int)__popcll(bal);
        __syncthreads();
        int waveoff = 0;
#pragma unroll
        for (int w = 0; w < 4; ++w) waveoff += (w < wave) ? s_wcnt[w] : 0;
        unsigned long long below_incl =
            (lane == 63) ? bal : (bal & ((1ull << (lane + 1)) - 1ull));
        int rank = waveoff + (int)__popcll(below_incl);  // inclusive rank
        float val = (coord && rank <= kstar) ? r : 0.0f;
#pragma unroll
        for (int off = 32; off > 0; off >>= 1) val += __shfl_down(val, off);
        if (lane == 0) wf[wave] = val;
        __syncthreads();
        if (tid == 0) total = wf[0] + wf[1] + wf[2] + wf[3];
    }
    if (tid == 0) out[0] = s_base + 5.0f * total;
}

extern "C" void kernel_launch(void* const* d_in, const int* in_sizes, int n_in,
                              void* d_out, int out_size, void* d_ws, size_t ws_size,
                              hipStream_t stream) {
    (void)in_sizes; (void)n_in; (void)out_size; (void)ws_size;
    const float* p = (const float*)d_in[0];   // predictions
    const float* t = (const float*)d_in[1];   // targets
    float4* stats = (float4*)d_ws;            // 6272 * 16 B = 100352 B
    float* out = (float*)d_out;

    yolo_k1<<<GRID1, 64, 0, stream>>>(p, t, stats);
    yolo_k2<<<1, 256, 0, stream>>>(stats, p, t, out);
}

// Round 6
// 213.090 us; speedup vs baseline: 1.0312x; 1.0312x over previous
//
#include <hip/hip_runtime.h>

// YOLOv1 loss: 802816 rows x 30 f32, two tensors, scalar out.
// R6: R2-R5 showed every compiler-visible memory path serializes:
//  - VGPR loads: allocator reuses regs (VGPR=24/32/36) -> ~4 outstanding.
//  - global_load_lds + ds_read: SIInsertWaitcnts inserts vmcnt(0) before
//    ds_read (LDS-DMA alias tracking) -> pipeline drained every tile.
// All plateaued at ~2.6 TB/s. Fix: ONE inline-asm block per thread with 30
// global_load_dwordx2 into 30 forced-distinct VGPR pairs + trailing
// s_waitcnt vmcnt(0) inside the block (uses data-depend on asm outputs, so
// nothing can be hoisted above the wait). 15.4 KB in flight per wave,
// 12 waves/CU -> memory system saturated; TLP hides the per-wave stall.

#define COLS 30
#define NB   3136              // 802816 rows / 256 rows per K1 block

// ---------------- per-row math on named scalars (bit-exact) ---------------
#define ROW_MATH_BODY                                                        \
    const float C = 1.0f / 7.0f;                                             \
    float conf = b2.x;                    /* T[4], exactly 0.0 or 1.0 */     \
    coord = (conf == 1.0f);                                                  \
    noo = 0.0f;                                                              \
    if (conf == 0.0f) {                                                      \
        float d4_ = a2.x - conf;                                             \
        float d9_ = a4.y - b4.y;                                             \
        noo = d4_ * d4_ + d9_ * d9_;                                         \
    }                                                                        \
    float T0 = b0.x, T1 = b0.y, T2v = b1.x, T3 = b1.y;                       \
    float tb0 = T0 * T0, tb1 = T1 * T1, tb2 = T2v * T2v, tb3 = T3 * T3;      \
    float tax = tb0 * C - tb2, tay = tb1 * C - tb3;                          \
    float tbx = tax * C + tb2, tby = tay * C + tb3;                          \
    float areaT = (tbx - tax) * (tby - tay);                                 \
    float pax0 = a0.x * C - a1.x, pay0 = a0.y * C - a1.y;                    \
    float pbx0 = pax0 * C + a1.x, pby0 = pay0 * C + a1.y;                    \
    float pax1 = a2.y * C - a3.y, pay1 = a3.x * C - a4.x;                    \
    float pbx1 = pax1 * C + a3.y, pby1 = pay1 * C + a4.x;                    \
    float ltx = fmaxf(pax0, tax), lty = fmaxf(pay0, tay);                    \
    float rbx = fminf(pbx0, tbx), rby = fminf(pby0, tby);                    \
    float wx = fmaxf(rbx - ltx, 0.0f), wy = fmaxf(rby - lty, 0.0f);          \
    float inter = wx * wy;                                                   \
    float areaP = (pbx0 - pax0) * (pby0 - pay0);                             \
    float iou0 = inter / (areaP + areaT - inter);                            \
    ltx = fmaxf(pax1, tax); lty = fmaxf(pay1, tay);                          \
    rbx = fminf(pbx1, tbx); rby = fminf(pby1, tby);                          \
    wx = fmaxf(rbx - ltx, 0.0f); wy = fmaxf(rby - lty, 0.0f);                \
    inter = wx * wy;                                                         \
    areaP = (pbx1 - pax1) * (pby1 - pay1);                                   \
    float iou1 = inter / (areaP + areaT - inter);                            \
    int idx = (iou1 > iou0) ? 1 : 0;      /* argmax, first on ties */        \
    float sx = idx ? a2.y : a0.x;                                            \
    float sy = idx ? a3.x : a0.y;                                            \
    float sw = idx ? a3.y : a1.x;                                            \
    float sh = idx ? a4.x : a1.y;                                            \
    float best = b5.x, pc = a5.x;         /* class argmax, strict > */       \
    CLS_STEP(b5.y,  a5.y)  CLS_STEP(b6.x,  a6.x)  CLS_STEP(b6.y,  a6.y)      \
    CLS_STEP(b7.x,  a7.x)  CLS_STEP(b7.y,  a7.y)  CLS_STEP(b8.x,  a8.x)      \
    CLS_STEP(b8.y,  a8.y)  CLS_STEP(b9.x,  a9.x)  CLS_STEP(b9.y,  a9.y)      \
    CLS_STEP(b10.x, a10.x) CLS_STEP(b10.y, a10.y) CLS_STEP(b11.x, a11.x)     \
    CLS_STEP(b11.y, a11.y) CLS_STEP(b12.x, a12.x) CLS_STEP(b12.y, a12.y)     \
    CLS_STEP(b13.x, a13.x) CLS_STEP(b13.y, a13.y) CLS_STEP(b14.x, a14.x)     \
    CLS_STEP(b14.y, a14.y)                                                   \
    float d0 = sx - T0, d1 = sy - T1, d2 = sw - T2v, d3 = sh - T3;           \
    float dc = pc - 1.0f;                                                    \
    r = d0 * d0 + d1 * d1 + d2 * d2 + d3 * d3 + 2.0f * dc * dc;

#define CLS_STEP(tv, pv) { float v_ = (tv); if (v_ > best) { best = v_; pc = (pv); } }

__device__ __forceinline__ void row_compute_vals(
    float2 a0, float2 a1, float2 a2, float2 a3, float2 a4,
    float2 a5, float2 a6, float2 a7, float2 a8, float2 a9,
    float2 a10, float2 a11, float2 a12, float2 a13, float2 a14,
    float2 b0, float2 b1, float2 b2, float2 b3, float2 b4,
    float2 b5, float2 b6, float2 b7, float2 b8, float2 b9,
    float2 b10, float2 b11, float2 b12, float2 b13, float2 b14,
    bool& coord, float& r, float& noo)
{
    ROW_MATH_BODY
}

// Plain-C++ row load+compute (used only in K2's 256-row fixup).
__device__ __forceinline__ void row_load_compute(
    const float* __restrict__ gp, const float* __restrict__ gt, long row,
    bool& coord, float& r, float& noo)
{
    const float2* P2 = (const float2*)(gp + row * (long)COLS);
    const float2* T2 = (const float2*)(gt + row * (long)COLS);
    float2 a0 = P2[0],  a1 = P2[1],  a2 = P2[2],  a3 = P2[3],  a4 = P2[4];
    float2 a5 = P2[5],  a6 = P2[6],  a7 = P2[7],  a8 = P2[8],  a9 = P2[9];
    float2 a10 = P2[10], a11 = P2[11], a12 = P2[12], a13 = P2[13], a14 = P2[14];
    float2 b0 = T2[0],  b1 = T2[1],  b2 = T2[2],  b3 = T2[3],  b4 = T2[4];
    float2 b5 = T2[5],  b6 = T2[6],  b7 = T2[7],  b8 = T2[8],  b9 = T2[9];
    float2 b10 = T2[10], b11 = T2[11], b12 = T2[12], b13 = T2[13], b14 = T2[14];
    ROW_MATH_BODY
}

// K1: per-block (256 rows) {coord count, sum coord r, noobj sum}.
// The 30-load + waitcnt asm block is the whole point — see header comment.
__global__ __launch_bounds__(256, 3) void yolo_k1(const float* __restrict__ gp,
                                                  const float* __restrict__ gt,
                                                  int* __restrict__ cnt,
                                                  float* __restrict__ sumR,
                                                  float* __restrict__ noo) {
    __shared__ float wr[4], wn[4];
    __shared__ int wc[4];
    int tid = threadIdx.x;
    long row = (long)blockIdx.x * 256 + tid;
    unsigned int voff = (unsigned int)(row * (long)(COLS * 4)); // byte offset

    float2 p0, p1, p2, p3, p4, p5, p6, p7, p8, p9, p10, p11, p12, p13, p14;
    float2 q0, q1, q2, q3, q4, q5, q6, q7, q8, q9, q10, q11, q12, q13, q14;
    asm volatile(
        "global_load_dwordx2 %0,  %[off], %[pb]\n\t"
        "global_load_dwordx2 %1,  %[off], %[pb] offset:8\n\t"
        "global_load_dwordx2 %2,  %[off], %[pb] offset:16\n\t"
        "global_load_dwordx2 %3,  %[off], %[pb] offset:24\n\t"
        "global_load_dwordx2 %4,  %[off], %[pb] offset:32\n\t"
        "global_load_dwordx2 %5,  %[off], %[pb] offset:40\n\t"
        "global_load_dwordx2 %6,  %[off], %[pb] offset:48\n\t"
        "global_load_dwordx2 %7,  %[off], %[pb] offset:56\n\t"
        "global_load_dwordx2 %8,  %[off], %[pb] offset:64\n\t"
        "global_load_dwordx2 %9,  %[off], %[pb] offset:72\n\t"
        "global_load_dwordx2 %10, %[off], %[pb] offset:80\n\t"
        "global_load_dwordx2 %11, %[off], %[pb] offset:88\n\t"
        "global_load_dwordx2 %12, %[off], %[pb] offset:96\n\t"
        "global_load_dwordx2 %13, %[off], %[pb] offset:104\n\t"
        "global_load_dwordx2 %14, %[off], %[pb] offset:112\n\t"
        "global_load_dwordx2 %15, %[off], %[tb]\n\t"
        "global_load_dwordx2 %16, %[off], %[tb] offset:8\n\t"
        "global_load_dwordx2 %17, %[off], %[tb] offset:16\n\t"
        "global_load_dwordx2 %18, %[off], %[tb] offset:24\n\t"
        "global_load_dwordx2 %19, %[off], %[tb] offset:32\n\t"
        "global_load_dwordx2 %20, %[off], %[tb] offset:40\n\t"
        "global_load_dwordx2 %21, %[off], %[tb] offset:48\n\t"
        "global_load_dwordx2 %22, %[off], %[tb] offset:56\n\t"
        "global_load_dwordx2 %23, %[off], %[tb] offset:64\n\t"
        "global_load_dwordx2 %24, %[off], %[tb] offset:72\n\t"
        "global_load_dwordx2 %25, %[off], %[tb] offset:80\n\t"
        "global_load_dwordx2 %26, %[off], %[tb] offset:88\n\t"
        "global_load_dwordx2 %27, %[off], %[tb] offset:96\n\t"
        "global_load_dwordx2 %28, %[off], %[tb] offset:104\n\t"
        "global_load_dwordx2 %29, %[off], %[tb] offset:112\n\t"
        "s_waitcnt vmcnt(0)"
        : "=v"(p0), "=v"(p1), "=v"(p2), "=v"(p3), "=v"(p4),
          "=v"(p5), "=v"(p6), "=v"(p7), "=v"(p8), "=v"(p9),
          "=v"(p10), "=v"(p11), "=v"(p12), "=v"(p13), "=v"(p14),
          "=v"(q0), "=v"(q1), "=v"(q2), "=v"(q3), "=v"(q4),
          "=v"(q5), "=v"(q6), "=v"(q7), "=v"(q8), "=v"(q9),
          "=v"(q10), "=v"(q11), "=v"(q12), "=v"(q13), "=v"(q14)
        : [off]"v"(voff), [pb]"s"(gp), [tb]"s"(gt)
        : "memory");

    bool coord; float r, nt;
    row_compute_vals(p0, p1, p2, p3, p4, p5, p6, p7, p8, p9,
                     p10, p11, p12, p13, p14,
                     q0, q1, q2, q3, q4, q5, q6, q7, q8, q9,
                     q10, q11, q12, q13, q14, coord, r, nt);
    float rl = coord ? r : 0.0f;

    unsigned long long bal = __ballot(coord);
    int c = (int)__popcll(bal);
#pragma unroll
    for (int off = 32; off > 0; off >>= 1) {
        rl += __shfl_down(rl, off);
        nt += __shfl_down(nt, off);
    }
    int wave = tid >> 6, lane = tid & 63;
    if (lane == 0) { wr[wave] = rl; wn[wave] = nt; wc[wave] = c; }
    __syncthreads();
    if (tid == 0) {
        cnt[blockIdx.x]  = wc[0] + wc[1] + wc[2] + wc[3];
        sumR[blockIdx.x] = wr[0] + wr[1] + wr[2] + wr[3];
        noo[blockIdx.x]  = wn[0] + wn[1] + wn[2] + wn[3];
    }
}

// K2: totals + scan + boundary-block fixup, single block (same as R4).
__global__ __launch_bounds__(256) void yolo_k2(const int* __restrict__ cnt,
                                               const float* __restrict__ sumR,
                                               const float* __restrict__ noo,
                                               const float* __restrict__ gp,
                                               const float* __restrict__ gt,
                                               float* __restrict__ out) {
    __shared__ int   wsum[4];
    __shared__ float wf[4], wn2[4];
    __shared__ int   s_bstar, s_kstar;
    __shared__ float s_base;
    __shared__ int   s_wcnt[4];
    int tid = threadIdx.x;
    int lane = tid & 63, wave = tid >> 6;
    if (tid == 0) { s_bstar = -1; s_kstar = 0; }

    const int PER = 13;                 // 256*13 = 3328 >= 3136
    int start = tid * PER;
    int end = min(NB, start + PER);

    int cloc = 0; float nloc = 0.0f;
    for (int i = start; i < end; ++i) { cloc += cnt[i]; nloc += noo[i]; }

    int incl = cloc;                    // inclusive shfl scan within wave
#pragma unroll
    for (int off = 1; off < 64; off <<= 1) {
        int v = __shfl_up(incl, off);
        if (lane >= off) incl += v;
    }
    if (lane == 63) wsum[wave] = incl;
    __syncthreads();                    // also orders s_bstar init vs walk
    int woff = 0;
#pragma unroll
    for (int w = 0; w < 4; ++w) woff += (w < wave) ? wsum[w] : 0;
    int ex = woff + incl - cloc;        // exclusive global prefix
    int n_obj = wsum[0] + wsum[1] + wsum[2] + wsum[3];
    int n_half = n_obj >> 1;

    float acc = 0.0f;
    int running = ex;
    for (int i = start; i < end; ++i) {
        int ci = cnt[i];
        if (ci > 0) {
            if (running + ci <= n_half) {
                acc += sumR[i];
            } else if (running < n_half) {  // exactly one thread ever
                s_bstar = i;
                s_kstar = n_half - running;
            }
        }
        running += ci;
    }

#pragma unroll
    for (int off = 32; off > 0; off >>= 1) {
        acc  += __shfl_down(acc, off);
        nloc += __shfl_down(nloc, off);
    }
    if (lane == 0) { wf[wave] = acc; wn2[wave] = nloc; }
    __syncthreads();
    if (tid == 0)
        s_base = 5.0f * (wf[0] + wf[1] + wf[2] + wf[3])
               + 0.5f * (wn2[0] + wn2[1] + wn2[2] + wn2[3]);
    __syncthreads();

    // Phase B: boundary block fixup (256 rows)
    int bstar = s_bstar, kstar = s_kstar;
    float total = 0.0f;
    if (bstar >= 0) {                    // uniform branch
        long row = (long)bstar * 256 + tid;
        bool coord; float r, nt;
        row_load_compute(gp, gt, row, coord, r, nt);
        unsigned long long bal = __ballot(coord);
        if (lane == 0) s_wcnt[wave] = (int)__popcll(bal);
        __syncthreads();
        int waveoff = 0;
#pragma unroll
        for (int w = 0; w < 4; ++w) waveoff += (w < wave) ? s_wcnt[w] : 0;
        unsigned long long below_incl =
            (lane == 63) ? bal : (bal & ((1ull << (lane + 1)) - 1ull));
        int rank = waveoff + (int)__popcll(below_incl);  // inclusive rank
        float val = (coord && rank <= kstar) ? r : 0.0f;
#pragma unroll
        for (int off = 32; off > 0; off >>= 1) val += __shfl_down(val, off);
        if (lane == 0) wf[wave] = val;
        __syncthreads();
        if (tid == 0) total = wf[0] + wf[1] + wf[2] + wf[3];
    }
    if (tid == 0) out[0] = s_base + 5.0f * total;
}

extern "C" void kernel_launch(void* const* d_in, const int* in_sizes, int n_in,
                              void* d_out, int out_size, void* d_ws, size_t ws_size,
                              hipStream_t stream) {
    (void)in_sizes; (void)n_in; (void)out_size; (void)ws_size;
    const float* p = (const float*)d_in[0];   // predictions
    const float* t = (const float*)d_in[1];   // targets
    char* ws = (char*)d_ws;                   // ~38 KB used
    int*   cnt  = (int*)ws;
    float* sumR = (float*)(ws + (size_t)NB * 4);
    float* noo  = (float*)(ws + (size_t)NB * 8);
    float* out  = (float*)d_out;

    yolo_k1<<<NB, 256, 0, stream>>>(p, t, cnt, sumR, noo);
    yolo_k2<<<1, 256, 0, stream>>>(cnt, sumR, noo, p, t, out);
}